// Round 9
// baseline (99.599 us; speedup 1.0000x reference)
//
#include <hip/hip_runtime.h>
#include <math.h>

typedef short bf16x8 __attribute__((ext_vector_type(8)));
typedef float f32x4 __attribute__((ext_vector_type(4)));
typedef unsigned int uint32;

#define BETA 10.0f
#define THRESH -80.0f
// Certificate: bound = max_ct(20*max_rows(acc) + c2_ct) + max_rows(-10*||x||^2)
// >= true max arg. A,B RTNE bf16 -> 20*|dot err| <= ~4; bf16-squared x2/c2
// (mfma diag) add <= ~10. Not fired => true arg <= -66 => contribution
// <= exp(-66)*1024*0.02 ~ 5e-27 << 1.5e-2. If fired, cold path is exact fp32.

__device__ __forceinline__ uint32 f2bf_rtne(float f) {
    uint32 u = __float_as_uint(f);
    u += 0x7FFFu + ((u >> 16) & 1u);
    return u >> 16;
}
__device__ __forceinline__ uint32 pk_rtne(float a, float b) {
    return f2bf_rtne(a) | (f2bf_rtne(b) << 16);
}
__device__ __forceinline__ f32x4 vmax4(f32x4 a, f32x4 b) {
    f32x4 r;
    r[0] = fmaxf(a[0], b[0]); r[1] = fmaxf(a[1], b[1]);
    r[2] = fmaxf(a[2], b[2]); r[3] = fmaxf(a[3], b[3]);
    return r;
}
#define MFMA __builtin_amdgcn_mfma_f32_16x16x32_bf16

// Single kernel, no staging: every MFMA fragment is a 32-B contiguous fp32
// chunk of x/centers, loaded per-lane straight from global (full cache-line
// utilization; centers L2-hot, x from HBM once, L1-reused across the 8
// waves). LDS = 1.5 KB 'red' only; ONE barrier. Grid 512 x 512 thr; wave =
// 128 rows x 128 cols; bf[8][2]+af[8][2]+acc[8] ~ 200 VGPR (2 waves/SIMD).
__global__ __launch_bounds__(512, 2) void rbfn_fused(
    const float* __restrict__ x,
    const float* __restrict__ centers,
    const float* __restrict__ W,
    const float* __restrict__ bias,
    float* __restrict__ out)
{
    __shared__ __align__(16) float red[384];   // [128 rows][3]

    const int tid = threadIdx.x;
    const int wv = tid >> 6;      // colgrp: 128 cols per wave
    const int lane = tid & 63;
    const int quad = lane >> 4;
    const int l15 = lane & 15;
    const int row0 = blockIdx.x * 128;
    const f32x4 z = {0.f, 0.f, 0.f, 0.f};

    // ---- B fragments: direct 32-B/lane loads from centers, convert ----
    bf16x8 bf[8][2];
    #pragma unroll
    for (int ct = 0; ct < 8; ++ct) {
        const float* cp = centers + (size_t)(wv * 128 + ct * 16 + l15) * 64 + quad * 8;
        #pragma unroll
        for (int kk = 0; kk < 2; ++kk) {
            const float4 u0 = *(const float4*)(cp + kk * 32);
            const float4 u1 = *(const float4*)(cp + kk * 32 + 4);
            union { bf16x8 v; uint4 u; } t;
            t.u.x = pk_rtne(u0.x, u0.y);
            t.u.y = pk_rtne(u0.z, u0.w);
            t.u.z = pk_rtne(u1.x, u1.y);
            t.u.w = pk_rtne(u1.z, u1.w);
            bf[ct][kk] = t.v;
        }
    }

    // ---- A fragments: direct 32-B/lane loads from x, convert ----
    bf16x8 af[8][2];
    #pragma unroll
    for (int rt = 0; rt < 8; ++rt) {
        const float* xp = x + (size_t)(row0 + rt * 16 + l15) * 64 + quad * 8;
        #pragma unroll
        for (int kk = 0; kk < 2; ++kk) {
            const float4 u0 = *(const float4*)(xp + kk * 32);
            const float4 u1 = *(const float4*)(xp + kk * 32 + 4);
            union { bf16x8 v; uint4 u; } t;
            t.u.x = pk_rtne(u0.x, u0.y);
            t.u.y = pk_rtne(u0.z, u0.w);
            t.u.z = pk_rtne(u1.x, u1.y);
            t.u.w = pk_rtne(u1.z, u1.w);
            af[rt][kk] = t.v;
        }
    }

    // ---- -BETA*||c_j||^2 via mfma(b,b) Gram diagonal ----
    float c2r[8];
    #pragma unroll
    for (int ct = 0; ct < 8; ++ct) {
        f32x4 d = MFMA(bf[ct][0], bf[ct][0], z, 0, 0, 0);
        d = MFMA(bf[ct][1], bf[ct][1], d, 0, 0, 0);
        const float dv = (l15 & 2) ? ((l15 & 1) ? d[3] : d[2])
                                   : ((l15 & 1) ? d[1] : d[0]);
        c2r[ct] = -BETA * __shfl(dv, (l15 >> 2) * 16 + l15);
    }

    // ---- prermax = -BETA * min ||x_row||^2 over this lane's 32 acc rows ----
    float mn = 1e30f;
    #pragma unroll
    for (int rt = 0; rt < 8; ++rt) {
        f32x4 d = MFMA(af[rt][0], af[rt][0], z, 0, 0, 0);
        d = MFMA(af[rt][1], af[rt][1], d, 0, 0, 0);
        #pragma unroll
        for (int reg = 0; reg < 4; ++reg)
            mn = fminf(mn, __shfl(d[reg], quad * 20 + reg));
    }
    const float prermax = -BETA * mn;

    // ---- wave 0: exact-ish x@Wx^T (hi/lo bf16 split) + bias -> red ----
    if (wv == 0) {
        const float bl = (l15 < 3) ? bias[l15] : 0.f;
        bf16x8 bwh[2], bwl[2];
        #pragma unroll
        for (int kk = 0; kk < 2; ++kk) {
            bf16x8 h, l;
            #pragma unroll
            for (int e = 0; e < 8; ++e) {
                const float w = (l15 < 3) ? W[l15 * 1088 + kk * 32 + quad * 8 + e] : 0.f;
                const uint32 hb = f2bf_rtne(w);
                h[e] = (short)hb;
                l[e] = (short)f2bf_rtne(w - __uint_as_float(hb << 16));
            }
            bwh[kk] = h; bwl[kk] = l;
        }
        #pragma unroll
        for (int rt = 0; rt < 8; ++rt) {
            f32x4 aw = MFMA(af[rt][0], bwh[0], z, 0, 0, 0);
            aw = MFMA(af[rt][1], bwh[1], aw, 0, 0, 0);
            aw = MFMA(af[rt][0], bwl[0], aw, 0, 0, 0);
            aw = MFMA(af[rt][1], bwl[1], aw, 0, 0, 0);
            if (l15 < 3) {
                #pragma unroll
                for (int reg = 0; reg < 4; ++reg)
                    red[(rt * 16 + quad * 4 + reg) * 3 + l15] = aw[reg] + bl;
            }
        }
    }

    // ---- hot loop: 8 col-tiles, zero memory ops, branch-free ----
    float gm = -1e30f;
    #pragma unroll
    for (int ct = 0; ct < 8; ++ct) {
        f32x4 acc[8];
        #pragma unroll
        for (int rt = 0; rt < 8; ++rt) {
            acc[rt] = MFMA(af[rt][0], bf[ct][0], z, 0, 0, 0);
            acc[rt] = MFMA(af[rt][1], bf[ct][1], acc[rt], 0, 0, 0);
        }
        f32x4 m0 = vmax4(vmax4(acc[0], acc[1]), vmax4(acc[2], acc[3]));
        f32x4 m1 = vmax4(vmax4(acc[4], acc[5]), vmax4(acc[6], acc[7]));
        m0 = vmax4(m0, m1);
        const float m = fmaxf(fmaxf(m0[0], m0[1]), fmaxf(m0[2], m0[3]));
        gm = fmaxf(gm, fmaf(2.0f * BETA, m, c2r[ct]));
    }
    const float bound = gm + prermax;

    // ---- cold exact path (statistically never; unconditional safety) ----
    if (__builtin_expect(__ballot(bound > THRESH) != 0ull, 0)) {
        #pragma clang loop unroll(disable)
        for (int ct = 0; ct < 8; ++ct) {
            const int j = wv * 128 + ct * 16 + l15;
            #pragma clang loop unroll(disable)
            for (int rr = 0; rr < 32; ++rr) {
                const int r = (rr >> 2) * 16 + quad * 4 + (rr & 3);
                const float* xr = x + (size_t)(row0 + r) * 64;
                const float* cr = centers + (size_t)j * 64;
                float d2 = 0.f;
                #pragma clang loop unroll(disable)
                for (int k = 0; k < 64; ++k) {
                    const float df = xr[k] - cr[k];
                    d2 = fmaf(df, df, d2);
                }
                const float arg = -BETA * d2;
                if (arg > -87.f) {
                    const float e = expf(arg);
                    atomicAdd(&red[r * 3 + 0], e * W[0 * 1088 + 64 + j]);
                    atomicAdd(&red[r * 3 + 1], e * W[1 * 1088 + 64 + j]);
                    atomicAdd(&red[r * 3 + 2], e * W[2 * 1088 + 64 + j]);
                }
            }
        }
    }
    __syncthreads();   // red complete

    // ---- coalesced float4 store ----
    if (tid < 96)
        ((float4*)out)[blockIdx.x * 96 + tid] = *((const float4*)red + tid);
}

extern "C" void kernel_launch(void* const* d_in, const int* in_sizes, int n_in,
                              void* d_out, int out_size, void* d_ws, size_t ws_size,
                              hipStream_t stream) {
    const float* x       = (const float*)d_in[0];
    const float* centers = (const float*)d_in[1];
    const float* W       = (const float*)d_in[2];
    const float* b       = (const float*)d_in[3];
    float* out = (float*)d_out;

    const int n = in_sizes[0] / 64;   // 65536 rows
    rbfn_fused<<<n / 128, 512, 0, stream>>>(x, centers, W, b, out);
}